// Round 3
// baseline (156.746 us; speedup 1.0000x reference)
//
#include <hip/hip_runtime.h>

// MyHingeLoss: cosine-similarity hinge loss, N=32768 rows, D=512, fp32.
// Memory-bound: 128 MiB mandatory reads -> ~21 us floor at 6.3 TB/s.
// One wave per row: 7 dots (out.tgt, out.out, tgt.tgt, out.t5[0..4]),
// t5 (target[:5], 10 KB) staged in LDS per block.

constexpr int D   = 512;
constexpr int NC  = 5;       // NUM_COMPARE
constexpr float MARGIN_F = 0.1f;
constexpr float EPS_F    = 1e-6f;

__global__ __launch_bounds__(256) void hinge_loss_kernel(
    const float* __restrict__ out, const float* __restrict__ tgt,
    float* __restrict__ result, int n, float inv_count)
{
  __shared__ float t5[NC * D];       // 10 KB: target rows 0..4
  __shared__ float tt5[NC];          // squared norms of t5 rows
  __shared__ float block_sum;

  const int tid = threadIdx.x;
  if (tid == 0) block_sum = 0.f;

  // Stage t5 into LDS: 2560 floats = 640 float4, 256 threads.
  for (int k = tid; k < NC * D / 4; k += 256) {
    reinterpret_cast<float4*>(t5)[k] = reinterpret_cast<const float4*>(tgt)[k];
  }
  __syncthreads();

  const int wid  = tid >> 6;   // wave 0..3
  const int lane = tid & 63;

  // Per-block tn5 computation (trivial: 5 rows x 512).
  for (int j = wid; j < NC; j += 4) {
    float s = 0.f;
    for (int k = lane; k < D; k += 64) {
      const float v = t5[j * D + k];
      s = fmaf(v, v, s);
    }
    #pragma unroll
    for (int off = 32; off; off >>= 1) s += __shfl_xor(s, off);
    if (lane == 0) tt5[j] = s;
  }
  __syncthreads();

  float tn5[NC];
  #pragma unroll
  for (int j = 0; j < NC; ++j) tn5[j] = sqrtf(tt5[j]);

  float wave_sum = 0.f;

  // One wave per row, grid-stride.
  const int stride = gridDim.x * 4;
  for (int i = blockIdx.x * 4 + wid; i < n; i += stride) {
    const float4* op = reinterpret_cast<const float4*>(out + (size_t)i * D);
    const float4* tp = reinterpret_cast<const float4*>(tgt + (size_t)i * D);
    float s_ot = 0.f, s_oo = 0.f, s_tt = 0.f;
    float s5[NC] = {0.f, 0.f, 0.f, 0.f, 0.f};
    #pragma unroll
    for (int c = 0; c < 2; ++c) {
      const float4 o = op[c * 64 + lane];   // coalesced: lane-contiguous 16B
      const float4 t = tp[c * 64 + lane];
      s_ot += o.x * t.x + o.y * t.y + o.z * t.z + o.w * t.w;
      s_oo += o.x * o.x + o.y * o.y + o.z * o.z + o.w * o.w;
      s_tt += t.x * t.x + t.y * t.y + t.z * t.z + t.w * t.w;
      #pragma unroll
      for (int j = 0; j < NC; ++j) {
        const float4 v = reinterpret_cast<const float4*>(t5 + j * D)[c * 64 + lane];
        s5[j] += o.x * v.x + o.y * v.y + o.z * v.z + o.w * v.w;
      }
    }
    // Butterfly-reduce the 8 partials across 64 lanes.
    #pragma unroll
    for (int off = 32; off; off >>= 1) {
      s_ot += __shfl_xor(s_ot, off);
      s_oo += __shfl_xor(s_oo, off);
      s_tt += __shfl_xor(s_tt, off);
      #pragma unroll
      for (int j = 0; j < NC; ++j) s5[j] += __shfl_xor(s5[j], off);
    }
    if (lane == 0) {
      const float on  = sqrtf(s_oo);
      const float tn  = sqrtf(s_tt);
      const float pos = s_ot / fmaxf(on * tn, EPS_F);
      #pragma unroll
      for (int j = 0; j < NC; ++j) {
        const float S = s5[j] / fmaxf(on * tn5[j], EPS_F);
        const float h = fmaxf(0.f, MARGIN_F - pos + S);
        wave_sum += (i == j) ? 0.f : h;
      }
    }
  }

  if (lane == 0) atomicAdd(&block_sum, wave_sum);  // LDS atomic, 4/block
  __syncthreads();
  if (tid == 0) atomicAdd(result, block_sum * inv_count);  // 1 global/block
}

extern "C" void kernel_launch(void* const* d_in, const int* in_sizes, int n_in,
                              void* d_out, int out_size, void* d_ws, size_t ws_size,
                              hipStream_t stream) {
  const float* out = (const float*)d_in[0];
  const float* tgt = (const float*)d_in[1];
  float* result = (float*)d_out;
  const int n = in_sizes[0] / D;                      // 32768
  const long long count = (long long)n * NC - (n < NC ? n : NC);
  const float inv_count = 1.0f / (float)count;

  // d_out is poisoned 0xAA before every timed call -> zero it (capture-legal).
  hipMemsetAsync(d_out, 0, sizeof(float), stream);

  hinge_loss_kernel<<<2048, 256, 0, stream>>>(out, tgt, result, n, inv_count);
}

// Round 8
// 154.361 us; speedup vs baseline: 1.0154x; 1.0154x over previous
//
#include <hip/hip_runtime.h>

// MyHingeLoss: cosine hinge loss, N=32768, D=512, fp32. Memory-bound floor
// ~21 us (128 MiB @ 6.3 TB/s). R3 evidence: 56 us REGARDLESS of L3
// residency -> bottleneck was 2048 contended same-address atomicAdds
// (2048 x ~65cy == 133k cy == measured 134k cy), not bandwidth.
// Fix: (a) zero atomics - per-wave partials to d_ws + tiny reduce kernel;
// (b) split-lane: 16 lanes/row, 4 rows/wave -> 8 shuffles/row (was 48),
// butterfly depth 4 (was 6); no LDS/barriers in the streaming kernel.

constexpr int D   = 512;           // floats per row (128 float4)
constexpr int NC  = 5;             // NUM_COMPARE
constexpr float MARGIN_F = 0.1f;
constexpr float EPS_F    = 1e-6f;

__global__ __launch_bounds__(256) void hinge_dots_kernel(
    const float* __restrict__ out, const float* __restrict__ tgt,
    float* __restrict__ wave_partial, int n)
{
  const int tid  = threadIdx.x;
  const int wid  = tid >> 6;
  const int lane = tid & 63;
  const int sub  = lane & 15;   // position within 16-lane group
  const int grp  = lane >> 4;   // 0..3: which row of the 4 this wave owns

  const float4* t5p = reinterpret_cast<const float4*>(tgt); // rows 0..4, stride 128 float4

  // --- per-wave tn5: no LDS, no barrier. group g computes ||t5[g]||^2,
  // every group redundantly computes ||t5[4]||^2. 10 KB -> L1-resident.
  float sq_own = 0.f, sq_4 = 0.f;
  #pragma unroll
  for (int c = 0; c < 8; ++c) {
    const float4 a = t5p[grp * 128 + c * 16 + sub];
    const float4 b = t5p[4   * 128 + c * 16 + sub];
    sq_own += a.x*a.x + a.y*a.y + a.z*a.z + a.w*a.w;
    sq_4   += b.x*b.x + b.y*b.y + b.z*b.z + b.w*b.w;
  }
  #pragma unroll
  for (int off = 8; off; off >>= 1) {   // xor-butterfly: sum replicated in group
    sq_own += __shfl_xor(sq_own, off);
    sq_4   += __shfl_xor(sq_4,   off);
  }
  float tn5[NC];
  #pragma unroll
  for (int j = 0; j < 4; ++j) tn5[j] = sqrtf(__shfl(sq_own, j * 16 + sub));
  tn5[4] = sqrtf(sq_4);

  // --- main: one row per 16-lane group, 4 rows per wave, exact-fit grid.
  const int gwave = blockIdx.x * 4 + wid;
  const int row   = gwave * 4 + grp;
  float acc = 0.f;
  if (row < n) {
    const float4* op = reinterpret_cast<const float4*>(out) + (size_t)row * 128;
    const float4* tp = reinterpret_cast<const float4*>(tgt) + (size_t)row * 128;
    float s_ot = 0.f, s_oo = 0.f, s_tt = 0.f;
    float s5[NC] = {0.f, 0.f, 0.f, 0.f, 0.f};
    #pragma unroll
    for (int c = 0; c < 8; ++c) {       // 16 independent 16B loads in flight
      const float4 o = op[c * 16 + sub];
      const float4 t = tp[c * 16 + sub];
      s_ot += o.x*t.x + o.y*t.y + o.z*t.z + o.w*t.w;
      s_oo += o.x*o.x + o.y*o.y + o.z*o.z + o.w*o.w;
      s_tt += t.x*t.x + t.y*t.y + t.z*t.z + t.w*t.w;
      #pragma unroll
      for (int j = 0; j < NC; ++j) {    // L1-hit reads of t5
        const float4 v = t5p[j * 128 + c * 16 + sub];
        s5[j] += o.x*v.x + o.y*v.y + o.z*v.z + o.w*v.w;
      }
    }
    // 4-step butterfly within each 16-lane group: 8 values, all 4 rows at once
    #pragma unroll
    for (int off = 8; off; off >>= 1) {
      s_ot += __shfl_xor(s_ot, off);
      s_oo += __shfl_xor(s_oo, off);
      s_tt += __shfl_xor(s_tt, off);
      #pragma unroll
      for (int j = 0; j < NC; ++j) s5[j] += __shfl_xor(s5[j], off);
    }
    const float on  = sqrtf(s_oo);
    const float tn  = sqrtf(s_tt);
    const float pos = s_ot / fmaxf(on * tn, EPS_F);
    float h = 0.f;
    #pragma unroll
    for (int j = 0; j < NC; ++j) {
      const float S = s5[j] / fmaxf(on * tn5[j], EPS_F);
      const float hv = fmaxf(0.f, MARGIN_F - pos + S);
      h += (row == j) ? 0.f : hv;
    }
    acc = (sub == 0) ? h : 0.f;         // sums are replicated; count once
  }
  // combine the 4 groups' lane-0 partials -> lane 0
  acc += __shfl_xor(acc, 16);
  acc += __shfl_xor(acc, 32);
  if (lane == 0) wave_partial[gwave] = acc;   // plain store, no atomic
}

__global__ __launch_bounds__(256) void reduce_kernel(
    const float* __restrict__ part, float* __restrict__ result,
    int nw, float inv_count)
{
  float s = 0.f;
  for (int i = threadIdx.x; i < nw; i += 256) s += part[i];
  #pragma unroll
  for (int off = 32; off; off >>= 1) s += __shfl_xor(s, off);
  __shared__ float ws[4];
  if ((threadIdx.x & 63) == 0) ws[threadIdx.x >> 6] = s;
  __syncthreads();
  if (threadIdx.x == 0) result[0] = (ws[0] + ws[1] + ws[2] + ws[3]) * inv_count;
}

extern "C" void kernel_launch(void* const* d_in, const int* in_sizes, int n_in,
                              void* d_out, int out_size, void* d_ws, size_t ws_size,
                              hipStream_t stream) {
  const float* out = (const float*)d_in[0];
  const float* tgt = (const float*)d_in[1];
  float* result = (float*)d_out;
  float* partials = (float*)d_ws;

  const int n = in_sizes[0] / D;                       // 32768
  const int blocks = (n + 15) / 16;                    // 16 rows per block
  const int nwaves = blocks * 4;                       // 8192 partial slots
  const long long count = (long long)n * NC - (n < NC ? n : NC);
  const float inv_count = 1.0f / (float)count;

  hinge_dots_kernel<<<blocks, 256, 0, stream>>>(out, tgt, partials, n);
  reduce_kernel<<<1, 256, 0, stream>>>(partials, result, nwaves, inv_count);
}